// Round 1
// baseline (3290.426 us; speedup 1.0000x reference)
//
#include <hip/hip_runtime.h>
#include <math.h>

#define EPSF 1e-7f
constexpr int BB = 2, HH = 512, WWC = 512;

// ---------------------------------------------------------------------------
// Direct 3x3 conv, pad=1, stride templated, fused bias + PReLU.
// Block = (64,4) threads, each thread computes 16 output channels at 1 pixel.
// Weights for the block's 16 output channels staged in LDS (broadcast reads).
// ---------------------------------------------------------------------------
template <int STRIDE>
__global__ void conv3x3_prelu(const float* __restrict__ in,
                              const float* __restrict__ wgt,
                              const float* __restrict__ bias,
                              const float* __restrict__ prelu_a, int aidx,
                              float* __restrict__ out,
                              int IC, int OC, int IH, int IW) {
    const int OH = IH / STRIDE, OW = IW / STRIDE;
    extern __shared__ float wsh[];  // 16 * IC * 9 floats
    const int oc0 = blockIdx.z * 16;
    const int nw = 16 * IC * 9;
    const float* wsrc = wgt + (size_t)oc0 * IC * 9;
    for (int i = threadIdx.y * 64 + threadIdx.x; i < nw; i += 256) wsh[i] = wsrc[i];
    __syncthreads();

    const int ox = blockIdx.x * 64 + threadIdx.x;
    const int tiles_y = OH / 4;
    const int oy = (blockIdx.y % tiles_y) * 4 + threadIdx.y;
    const int b = blockIdx.y / tiles_y;

    float acc[16];
#pragma unroll
    for (int j = 0; j < 16; j++) acc[j] = bias[oc0 + j];

    const float* inb = in + (size_t)b * IC * IH * IW;
    const int iy0 = oy * STRIDE - 1, ix0 = ox * STRIDE - 1;
    for (int ic = 0; ic < IC; ic++) {
        const float* ip = inb + (size_t)ic * IH * IW;
        float v[9];
#pragma unroll
        for (int ky = 0; ky < 3; ky++) {
            int iy = iy0 + ky;
            bool yok = (unsigned)iy < (unsigned)IH;
#pragma unroll
            for (int kx = 0; kx < 3; kx++) {
                int ix = ix0 + kx;
                v[ky * 3 + kx] =
                    (yok && (unsigned)ix < (unsigned)IW) ? ip[iy * IW + ix] : 0.f;
            }
        }
#pragma unroll
        for (int j = 0; j < 16; j++) {
            const float* wj = wsh + (j * IC + ic) * 9;
            float a = acc[j];
#pragma unroll
            for (int k = 0; k < 9; k++) a = fmaf(v[k], wj[k], a);
            acc[j] = a;
        }
    }
    const float al = prelu_a[aidx];
    float* ob = out + (((size_t)b * OC + oc0) * OH + oy) * OW + ox;
#pragma unroll
    for (int j = 0; j < 16; j++) {
        float y = acc[j];
        y = y >= 0.f ? y : al * y;
        ob[(size_t)j * OH * OW] = y;
    }
}

// ---------------------------------------------------------------------------
// z = param_scale * mean_c |(2*i0-1) - backwarp(2*i1-1, flow)|
// backwarp of affine map: backwarp(2x-1) == 2*backwarp(x)-1 (weights sum to 1)
// ---------------------------------------------------------------------------
__global__ void compute_z_kernel(const float* __restrict__ i0,
                                 const float* __restrict__ i1,
                                 const float* __restrict__ flow,
                                 const float* __restrict__ pscale,
                                 float* __restrict__ z) {
    int idx = blockIdx.x * blockDim.x + threadIdx.x;
    const int n = BB * HH * WWC;
    if (idx >= n) return;
    int x = idx % WWC, y = (idx / WWC) % HH, b = idx / (WWC * HH);
    const float* fb = flow + (size_t)b * 2 * HH * WWC;
    float fx = fb[y * WWC + x];
    float fy = fb[HH * WWC + y * WWC + x];
    float px = fminf(fmaxf(x + fx, 0.f), WWC - 1.f);
    float py = fminf(fmaxf(y + fy, 0.f), HH - 1.f);
    float x0f = floorf(px), y0f = floorf(py);
    int x0 = (int)x0f, y0 = (int)y0f;
    int x1 = min(x0 + 1, WWC - 1), y1 = min(y0 + 1, HH - 1);
    float wx = px - x0f, wy = py - y0f;
    float w00 = (1.f - wx) * (1.f - wy), w10 = wx * (1.f - wy);
    float w01 = (1.f - wx) * wy, w11 = wx * wy;
    const float* ib0 = i0 + (size_t)b * 3 * HH * WWC;
    const float* ib1 = i1 + (size_t)b * 3 * HH * WWC;
    float err = 0.f;
#pragma unroll
    for (int c = 0; c < 3; c++) {
        const float* sp = ib1 + (size_t)c * HH * WWC;
        float wv = sp[y0 * WWC + x0] * w00 + sp[y0 * WWC + x1] * w10 +
                   sp[y1 * WWC + x0] * w01 + sp[y1 * WWC + x1] * w11;
        float p0 = 2.f * ib0[(size_t)c * HH * WWC + y * WWC + x] - 1.f;
        err += fabsf(p0 - (2.f * wv - 1.f));
    }
    z[idx] = pscale[0] * (err * (1.f / 3.f));
}

// ---------------------------------------------------------------------------
// Forward splat of (-f * e^z, e^z) with flow f = tt*flow_in; z resampled
// bilinearly (half-pixel coords) for s>0. acc layout (B,3,hh,ww).
// ---------------------------------------------------------------------------
__global__ void splat_kernel(const float* __restrict__ flow,
                             const float* __restrict__ z,
                             const float* __restrict__ tptr, int dir,
                             float* __restrict__ acc, int s, int hh, int ww) {
    int idx = blockIdx.x * blockDim.x + threadIdx.x;
    const int n = BB * hh * ww;
    if (idx >= n) return;
    int x = idx % ww, y = (idx / ww) % hh, b = idx / (ww * hh);
    float tt = tptr[b];
    if (dir) tt = 1.f - tt;
    const float* fb = flow + (size_t)b * 2 * hh * ww;
    float fx = tt * fb[y * ww + x];
    float fy = tt * fb[hh * ww + y * ww + x];
    float zz;
    if (s == 0) {
        zz = z[((size_t)b * HH + y) * WWC + x];
    } else {
        float sc = (float)(1 << s);
        float px = fminf(fmaxf((x + 0.5f) * sc - 0.5f, 0.f), WWC - 1.f);
        float py = fminf(fmaxf((y + 0.5f) * sc - 0.5f, 0.f), HH - 1.f);
        float x0f = floorf(px), y0f = floorf(py);
        int x0 = (int)x0f, y0 = (int)y0f;
        int x1 = min(x0 + 1, WWC - 1), y1 = min(y0 + 1, HH - 1);
        float wx = px - x0f, wy = py - y0f;
        const float* zp = z + (size_t)b * HH * WWC;
        zz = zp[y0 * WWC + x0] * (1.f - wx) * (1.f - wy) +
             zp[y0 * WWC + x1] * wx * (1.f - wy) +
             zp[y1 * WWC + x0] * (1.f - wx) * wy + zp[y1 * WWC + x1] * wx * wy;
    }
    float ez = expf(zz);
    float vx = -fx * ez, vy = -fy * ez;
    float tx = x + fx, ty = y + fy;
    float x0f = floorf(tx), y0f = floorf(ty);
    int x0 = (int)x0f, y0 = (int)y0f;
    int x1 = x0 + 1, y1 = y0 + 1;
    float wx1 = tx - x0f, wy1 = ty - y0f;
    float wx0 = 1.f - wx1, wy0 = 1.f - wy1;
    float* ab = acc + (size_t)b * 3 * hh * ww;
    const int plane = hh * ww;
    int cxs[4] = {x0, x1, x0, x1};
    int cys[4] = {y0, y0, y1, y1};
    float cws[4] = {wx0 * wy0, wx1 * wy0, wx0 * wy1, wx1 * wy1};
#pragma unroll
    for (int k = 0; k < 4; k++) {
        int cx = cxs[k], cy = cys[k];
        float w = cws[k];
        if (cx >= 0 && cx < ww && cy >= 0 && cy < hh && w != 0.f) {
            int o = cy * ww + cx;
            atomicAdd(ab + o, vx * w);
            atomicAdd(ab + plane + o, vy * w);
            atomicAdd(ab + 2 * plane + o, ez * w);
        }
    }
}

// ---------------------------------------------------------------------------
// flow_t0 = acc[0:2]/(acc[2]+eps); out[:,coff:coff+C] = backwarp(src, flow_t0)
// ---------------------------------------------------------------------------
__global__ void backwarp_out_kernel(const float* __restrict__ acc,
                                    const float* __restrict__ src,
                                    float* __restrict__ out, int C, int hh,
                                    int ww, int OCL, int coff) {
    int idx = blockIdx.x * blockDim.x + threadIdx.x;
    const int n = BB * hh * ww;
    if (idx >= n) return;
    int x = idx % ww, y = (idx / ww) % hh, b = idx / (ww * hh);
    const int plane = hh * ww;
    const float* ab = acc + (size_t)b * 3 * plane;
    int o = y * ww + x;
    float den = ab[2 * plane + o] + EPSF;
    float fx = ab[o] / den;
    float fy = ab[plane + o] / den;
    float px = fminf(fmaxf(x + fx, 0.f), ww - 1.f);
    float py = fminf(fmaxf(y + fy, 0.f), hh - 1.f);
    float x0f = floorf(px), y0f = floorf(py);
    int x0 = (int)x0f, y0 = (int)y0f;
    int x1 = min(x0 + 1, ww - 1), y1 = min(y0 + 1, hh - 1);
    float wx = px - x0f, wy = py - y0f;
    float w00 = (1.f - wx) * (1.f - wy), w10 = wx * (1.f - wy);
    float w01 = (1.f - wx) * wy, w11 = wx * wy;
    int i00 = y0 * ww + x0, i10 = y0 * ww + x1, i01 = y1 * ww + x0,
        i11 = y1 * ww + x1;
    const float* sb = src + (size_t)b * C * plane;
    float* ob = out + (((size_t)b * OCL + coff) * (size_t)plane) + o;
    for (int c = 0; c < C; c++) {
        const float* sp = sb + (size_t)c * plane;
        float v = sp[i00] * w00 + sp[i10] * w10 + sp[i01] * w01 + sp[i11] * w11;
        ob[(size_t)c * plane] = v;
    }
}

// ---------------------------------------------------------------------------
extern "C" void kernel_launch(void* const* d_in, const int* in_sizes, int n_in,
                              void* d_out, int out_size, void* d_ws,
                              size_t ws_size, hipStream_t stream) {
    const float* input0 = (const float*)d_in[0];
    const float* input1 = (const float*)d_in[1];
    const float* tgt = (const float*)d_in[2];
    const float* flows[2][3] = {
        {(const float*)d_in[3], (const float*)d_in[4], (const float*)d_in[5]},
        {(const float*)d_in[6], (const float*)d_in[7], (const float*)d_in[8]}};
    const float* w[6];
    const float* bs[6];
    for (int i = 0; i < 6; i++) {
        w[i] = (const float*)d_in[9 + 2 * i];
        bs[i] = (const float*)d_in[10 + 2 * i];
    }
    const float* prelu_a = (const float*)d_in[21];
    const float* pscale = (const float*)d_in[22];
    float* out = (float*)d_out;
    float* wsp = (float*)d_ws;

    // Workspace layout (floats): 59,244,544 total (~237 MB)
    float* fea1[2] = {wsp, wsp + 16777216};              // (2,32,512,512) each
    float* fea2[2] = {wsp + 33554432, wsp + 41943040};   // (2,64,256,256) each
    float* fea3[2] = {wsp + 50331648, wsp + 53477376};   // (2,96,128,128) each
    float* zb[2] = {wsp + 56623104, wsp + 57147392};     // (2,512,512) each
    float* acc = wsp + 57671680;                          // (2,3,512,512)
    float* tmp = out;  // conv ping-pong scratch; overwritten by outputs later

    auto conv = [&](int stride, const float* in, int li, float* o, int IC,
                    int OC, int IH, int IW) {
        int OH = IH / stride, OW = IW / stride;
        dim3 blk(64, 4);
        dim3 grd(OW / 64, (OH / 4) * BB, OC / 16);
        size_t sm = (size_t)16 * IC * 9 * sizeof(float);
        if (stride == 1)
            conv3x3_prelu<1><<<grd, blk, sm, stream>>>(in, w[li], bs[li],
                                                       prelu_a, li, o, IC, OC,
                                                       IH, IW);
        else
            conv3x3_prelu<2><<<grd, blk, sm, stream>>>(in, w[li], bs[li],
                                                       prelu_a, li, o, IC, OC,
                                                       IH, IW);
    };

    const float* inp[2] = {input0, input1};
    for (int i = 0; i < 2; i++) {
        conv(1, inp[i], 0, tmp, 3, 32, 512, 512);
        conv(1, tmp, 1, fea1[i], 32, 32, 512, 512);
        conv(2, fea1[i], 2, tmp, 32, 64, 512, 512);
        conv(1, tmp, 3, fea2[i], 64, 64, 256, 256);
        conv(2, fea2[i], 4, tmp, 64, 96, 256, 256);
        conv(1, tmp, 5, fea3[i], 96, 96, 128, 128);
    }

    {
        int n = BB * HH * WWC;
        compute_z_kernel<<<(n + 255) / 256, 256, 0, stream>>>(
            input0, input1, flows[0][0], pscale, zb[0]);
        compute_z_kernel<<<(n + 255) / 256, 256, 0, stream>>>(
            input1, input0, flows[1][0], pscale, zb[1]);
    }

    const size_t l1off = (size_t)BB * 70 * 512 * 512;            // 36,700,160
    const size_t l2off = l1off + (size_t)BB * 128 * 256 * 256;   // 53,477,376

    for (int d = 0; d < 2; d++) {
        for (int s = 0; s < 3; s++) {
            int hh = HH >> s, ww = WWC >> s;
            int n = BB * hh * ww;
            hipMemsetAsync(acc, 0, (size_t)BB * 3 * hh * ww * sizeof(float),
                           stream);
            splat_kernel<<<(n + 255) / 256, 256, 0, stream>>>(
                flows[d][s], zb[d], tgt, d, acc, s, hh, ww);
            if (s == 0) {
                backwarp_out_kernel<<<(n + 255) / 256, 256, 0, stream>>>(
                    acc, inp[d], out, 3, 512, 512, 70, d ? 35 : 0);
                backwarp_out_kernel<<<(n + 255) / 256, 256, 0, stream>>>(
                    acc, fea1[d], out, 32, 512, 512, 70, d ? 38 : 3);
            } else if (s == 1) {
                backwarp_out_kernel<<<(n + 255) / 256, 256, 0, stream>>>(
                    acc, fea2[d], out + l1off, 64, 256, 256, 128, d ? 64 : 0);
            } else {
                backwarp_out_kernel<<<(n + 255) / 256, 256, 0, stream>>>(
                    acc, fea3[d], out + l2off, 96, 128, 128, 192, d ? 96 : 0);
            }
        }
    }
}

// Round 2
// 2249.638 us; speedup vs baseline: 1.4626x; 1.4626x over previous
//
#include <hip/hip_runtime.h>
#include <math.h>

#define EPSF 1e-7f
constexpr int BB = 2, HH = 512, WWC = 512;

// ---------------------------------------------------------------------------
// Direct 3x3 conv, pad=1, fused bias + PReLU, register-tiled.
// Block = (64,4). Each thread computes YT output rows (same x) for OCT
// output channels. Weights for the block's OCT channels staged in LDS;
// each 9-weight LDS read is reused across YT rows (YT*9 FMAs per 3 ds_reads).
// ---------------------------------------------------------------------------
template <int S, int OCT, int YT>
__global__ __launch_bounds__(256) void conv3x3_prelu(
    const float* __restrict__ in, const float* __restrict__ wgt,
    const float* __restrict__ bias, const float* __restrict__ prelu_a,
    int aidx, float* __restrict__ out, int IC, int OC, int IH, int IW) {
    const int OH = IH / S, OW = IW / S;
    extern __shared__ float wsh[];  // OCT * IC * 9 floats
    const int oc0 = blockIdx.z * OCT;
    const int nw = OCT * IC * 9;
    const float* wsrc = wgt + (size_t)oc0 * IC * 9;
    for (int i = threadIdx.y * 64 + threadIdx.x; i < nw; i += 256)
        wsh[i] = wsrc[i];
    __syncthreads();

    const int ox = blockIdx.x * 64 + threadIdx.x;
    const int BROWS = 4 * YT;
    const int tiles_y = OH / BROWS;
    const int oy0 = (blockIdx.y % tiles_y) * BROWS + threadIdx.y * YT;
    const int b = blockIdx.y / tiles_y;

    float acc[OCT][YT];
#pragma unroll
    for (int j = 0; j < OCT; j++) {
        float bj = bias[oc0 + j];
#pragma unroll
        for (int yy = 0; yy < YT; yy++) acc[j][yy] = bj;
    }

    constexpr int R = YT * S + 2;  // input rows needed
    const float* inb = in + (size_t)b * IC * IH * IW;
    const int iy0 = oy0 * S - 1, ix0 = ox * S - 1;

    for (int ic = 0; ic < IC; ic++) {
        const float* ip = inb + (size_t)ic * IH * IW;
        float v[R][3];
#pragma unroll
        for (int r = 0; r < R; r++) {
            const int iy = iy0 + r;
            const bool yok = (unsigned)iy < (unsigned)IH;
            const float* rp = ip + iy * IW;
#pragma unroll
            for (int c = 0; c < 3; c++) {
                const int ix = ix0 + c;
                v[r][c] = (yok && (unsigned)ix < (unsigned)IW) ? rp[ix] : 0.f;
            }
        }
#pragma unroll
        for (int j = 0; j < OCT; j++) {
            const float* wj = wsh + (j * IC + ic) * 9;
            float w[9];
#pragma unroll
            for (int k = 0; k < 9; k++) w[k] = wj[k];
#pragma unroll
            for (int yy = 0; yy < YT; yy++) {
                float a = acc[j][yy];
#pragma unroll
                for (int ky = 0; ky < 3; ky++)
#pragma unroll
                    for (int kx = 0; kx < 3; kx++)
                        a = fmaf(v[yy * S + ky][kx], w[ky * 3 + kx], a);
                acc[j][yy] = a;
            }
        }
    }
    const float al = prelu_a[aidx];
    float* ob = out + (((size_t)b * OC + oc0) * OH + oy0) * OW + ox;
#pragma unroll
    for (int j = 0; j < OCT; j++)
#pragma unroll
        for (int yy = 0; yy < YT; yy++) {
            float y = acc[j][yy];
            y = y >= 0.f ? y : al * y;
            ob[(size_t)j * OH * OW + (size_t)yy * OW] = y;
        }
}

// ---------------------------------------------------------------------------
// z = param_scale * mean_c |(2*i0-1) - backwarp(2*i1-1, flow)| for BOTH
// directions in one launch (blockIdx.y = direction).
// ---------------------------------------------------------------------------
__global__ void compute_z2_kernel(const float* __restrict__ in0,
                                  const float* __restrict__ in1,
                                  const float* __restrict__ f01,
                                  const float* __restrict__ f10,
                                  const float* __restrict__ pscale,
                                  float* __restrict__ z0,
                                  float* __restrict__ z1) {
    int idx = blockIdx.x * blockDim.x + threadIdx.x;
    const int n = BB * HH * WWC;
    if (idx >= n) return;
    const int dir = blockIdx.y;
    const float* i0 = dir ? in1 : in0;
    const float* i1 = dir ? in0 : in1;
    const float* flow = dir ? f10 : f01;
    float* z = dir ? z1 : z0;
    int x = idx % WWC, y = (idx / WWC) % HH, b = idx / (WWC * HH);
    const float* fb = flow + (size_t)b * 2 * HH * WWC;
    float fx = fb[y * WWC + x];
    float fy = fb[HH * WWC + y * WWC + x];
    float px = fminf(fmaxf(x + fx, 0.f), WWC - 1.f);
    float py = fminf(fmaxf(y + fy, 0.f), HH - 1.f);
    float x0f = floorf(px), y0f = floorf(py);
    int x0 = (int)x0f, y0 = (int)y0f;
    int x1 = min(x0 + 1, WWC - 1), y1 = min(y0 + 1, HH - 1);
    float wx = px - x0f, wy = py - y0f;
    float w00 = (1.f - wx) * (1.f - wy), w10 = wx * (1.f - wy);
    float w01 = (1.f - wx) * wy, w11 = wx * wy;
    const float* ib0 = i0 + (size_t)b * 3 * HH * WWC;
    const float* ib1 = i1 + (size_t)b * 3 * HH * WWC;
    float err = 0.f;
#pragma unroll
    for (int c = 0; c < 3; c++) {
        const float* sp = ib1 + (size_t)c * HH * WWC;
        float wv = sp[y0 * WWC + x0] * w00 + sp[y0 * WWC + x1] * w10 +
                   sp[y1 * WWC + x0] * w01 + sp[y1 * WWC + x1] * w11;
        float p0 = 2.f * ib0[(size_t)c * HH * WWC + y * WWC + x] - 1.f;
        err += fabsf(p0 - (2.f * wv - 1.f));
    }
    z[idx] = pscale[0] * (err * (1.f / 3.f));
}

// ---------------------------------------------------------------------------
// Forward splat of (-f * e^z, e^z) with flow f = tt*flow_in; z resampled
// bilinearly (half-pixel coords) for s>0. acc layout (B,3,hh,ww).
// ---------------------------------------------------------------------------
__global__ void splat_kernel(const float* __restrict__ flow,
                             const float* __restrict__ z,
                             const float* __restrict__ tptr, int dir,
                             float* __restrict__ acc, int s, int hh, int ww) {
    int idx = blockIdx.x * blockDim.x + threadIdx.x;
    const int n = BB * hh * ww;
    if (idx >= n) return;
    int x = idx % ww, y = (idx / ww) % hh, b = idx / (ww * hh);
    float tt = tptr[b];
    if (dir) tt = 1.f - tt;
    const float* fb = flow + (size_t)b * 2 * hh * ww;
    float fx = tt * fb[y * ww + x];
    float fy = tt * fb[hh * ww + y * ww + x];
    float zz;
    if (s == 0) {
        zz = z[((size_t)b * HH + y) * WWC + x];
    } else {
        float sc = (float)(1 << s);
        float px = fminf(fmaxf((x + 0.5f) * sc - 0.5f, 0.f), WWC - 1.f);
        float py = fminf(fmaxf((y + 0.5f) * sc - 0.5f, 0.f), HH - 1.f);
        float x0f = floorf(px), y0f = floorf(py);
        int x0 = (int)x0f, y0 = (int)y0f;
        int x1 = min(x0 + 1, WWC - 1), y1 = min(y0 + 1, HH - 1);
        float wx = px - x0f, wy = py - y0f;
        const float* zp = z + (size_t)b * HH * WWC;
        zz = zp[y0 * WWC + x0] * (1.f - wx) * (1.f - wy) +
             zp[y0 * WWC + x1] * wx * (1.f - wy) +
             zp[y1 * WWC + x0] * (1.f - wx) * wy + zp[y1 * WWC + x1] * wx * wy;
    }
    float ez = expf(zz);
    float vx = -fx * ez, vy = -fy * ez;
    float tx = x + fx, ty = y + fy;
    float x0f = floorf(tx), y0f = floorf(ty);
    int x0 = (int)x0f, y0 = (int)y0f;
    int x1 = x0 + 1, y1 = y0 + 1;
    float wx1 = tx - x0f, wy1 = ty - y0f;
    float wx0 = 1.f - wx1, wy0 = 1.f - wy1;
    float* ab = acc + (size_t)b * 3 * hh * ww;
    const int plane = hh * ww;
    int cxs[4] = {x0, x1, x0, x1};
    int cys[4] = {y0, y0, y1, y1};
    float cws[4] = {wx0 * wy0, wx1 * wy0, wx0 * wy1, wx1 * wy1};
#pragma unroll
    for (int k = 0; k < 4; k++) {
        int cx = cxs[k], cy = cys[k];
        float w = cws[k];
        if (cx >= 0 && cx < ww && cy >= 0 && cy < hh && w != 0.f) {
            int o = cy * ww + cx;
            atomicAdd(ab + o, vx * w);
            atomicAdd(ab + plane + o, vy * w);
            atomicAdd(ab + 2 * plane + o, ez * w);
        }
    }
}

// ---------------------------------------------------------------------------
// flow_t0 = acc[0:2]/(acc[2]+eps); out[:,coff:coff+C] = backwarp(src, flow_t0)
// ---------------------------------------------------------------------------
__global__ void backwarp_out_kernel(const float* __restrict__ acc,
                                    const float* __restrict__ src,
                                    float* __restrict__ out, int C, int hh,
                                    int ww, int OCL, int coff) {
    int idx = blockIdx.x * blockDim.x + threadIdx.x;
    const int n = BB * hh * ww;
    if (idx >= n) return;
    int x = idx % ww, y = (idx / ww) % hh, b = idx / (ww * hh);
    const int plane = hh * ww;
    const float* ab = acc + (size_t)b * 3 * plane;
    int o = y * ww + x;
    float den = ab[2 * plane + o] + EPSF;
    float fx = ab[o] / den;
    float fy = ab[plane + o] / den;
    float px = fminf(fmaxf(x + fx, 0.f), ww - 1.f);
    float py = fminf(fmaxf(y + fy, 0.f), hh - 1.f);
    float x0f = floorf(px), y0f = floorf(py);
    int x0 = (int)x0f, y0 = (int)y0f;
    int x1 = min(x0 + 1, ww - 1), y1 = min(y0 + 1, hh - 1);
    float wx = px - x0f, wy = py - y0f;
    float w00 = (1.f - wx) * (1.f - wy), w10 = wx * (1.f - wy);
    float w01 = (1.f - wx) * wy, w11 = wx * wy;
    int i00 = y0 * ww + x0, i10 = y0 * ww + x1, i01 = y1 * ww + x0,
        i11 = y1 * ww + x1;
    const float* sb = src + (size_t)b * C * plane;
    float* ob = out + (((size_t)b * OCL + coff) * (size_t)plane) + o;
    for (int c = 0; c < C; c++) {
        const float* sp = sb + (size_t)c * plane;
        float v = sp[i00] * w00 + sp[i10] * w10 + sp[i01] * w01 + sp[i11] * w11;
        ob[(size_t)c * plane] = v;
    }
}

// ---------------------------------------------------------------------------
extern "C" void kernel_launch(void* const* d_in, const int* in_sizes, int n_in,
                              void* d_out, int out_size, void* d_ws,
                              size_t ws_size, hipStream_t stream) {
    const float* input0 = (const float*)d_in[0];
    const float* input1 = (const float*)d_in[1];
    const float* tgt = (const float*)d_in[2];
    const float* flows[2][3] = {
        {(const float*)d_in[3], (const float*)d_in[4], (const float*)d_in[5]},
        {(const float*)d_in[6], (const float*)d_in[7], (const float*)d_in[8]}};
    const float* w[6];
    const float* bs[6];
    for (int i = 0; i < 6; i++) {
        w[i] = (const float*)d_in[9 + 2 * i];
        bs[i] = (const float*)d_in[10 + 2 * i];
    }
    const float* prelu_a = (const float*)d_in[21];
    const float* pscale = (const float*)d_in[22];
    float* out = (float*)d_out;
    float* wsp = (float*)d_ws;

    // Workspace layout (floats): 59,244,544 total (~237 MB)
    float* fea1[2] = {wsp, wsp + 16777216};              // (2,32,512,512) each
    float* fea2[2] = {wsp + 33554432, wsp + 41943040};   // (2,64,256,256) each
    float* fea3[2] = {wsp + 50331648, wsp + 53477376};   // (2,96,128,128) each
    float* zb[2] = {wsp + 56623104, wsp + 57147392};     // (2,512,512) each
    float* acc = wsp + 57671680;                          // (2,3,512,512)
    float* tmp = out;  // conv ping-pong scratch; overwritten by outputs later

    // conv<STRIDE, OCT(out-ch/thread), YT(rows/thread)>
    auto conv = [&](int stride, int oct, int yt, const float* in, int li,
                    float* o, int IC, int OC, int IH, int IW) {
        int OH = IH / stride, OW = IW / stride;
        int brows = 4 * yt;
        dim3 blk(64, 4);
        dim3 grd(OW / 64, (OH / brows) * BB, OC / oct);
        size_t sm = (size_t)oct * IC * 9 * sizeof(float);
        if (stride == 1 && oct == 16 && yt == 4)
            conv3x3_prelu<1, 16, 4><<<grd, blk, sm, stream>>>(
                in, w[li], bs[li], prelu_a, li, o, IC, OC, IH, IW);
        else if (stride == 2 && oct == 16 && yt == 4)
            conv3x3_prelu<2, 16, 4><<<grd, blk, sm, stream>>>(
                in, w[li], bs[li], prelu_a, li, o, IC, OC, IH, IW);
        else if (stride == 2 && oct == 8 && yt == 2)
            conv3x3_prelu<2, 8, 2><<<grd, blk, sm, stream>>>(
                in, w[li], bs[li], prelu_a, li, o, IC, OC, IH, IW);
        else
            conv3x3_prelu<1, 8, 2><<<grd, blk, sm, stream>>>(
                in, w[li], bs[li], prelu_a, li, o, IC, OC, IH, IW);
    };

    const float* inp[2] = {input0, input1};
    for (int i = 0; i < 2; i++) {
        conv(1, 16, 4, inp[i], 0, tmp, 3, 32, 512, 512);
        conv(1, 16, 4, tmp, 1, fea1[i], 32, 32, 512, 512);
        conv(2, 16, 4, fea1[i], 2, tmp, 32, 64, 512, 512);
        conv(1, 16, 4, tmp, 3, fea2[i], 64, 64, 256, 256);
        conv(2, 8, 2, fea2[i], 4, tmp, 64, 96, 256, 256);
        conv(1, 8, 2, tmp, 5, fea3[i], 96, 96, 128, 128);
    }

    {
        int n = BB * HH * WWC;
        dim3 grd((n + 255) / 256, 2);
        compute_z2_kernel<<<grd, 256, 0, stream>>>(
            input0, input1, flows[0][0], flows[1][0], pscale, zb[0], zb[1]);
    }

    const size_t l1off = (size_t)BB * 70 * 512 * 512;            // 36,700,160
    const size_t l2off = l1off + (size_t)BB * 128 * 256 * 256;   // 53,477,376

    for (int d = 0; d < 2; d++) {
        for (int s = 0; s < 3; s++) {
            int hh = HH >> s, ww = WWC >> s;
            int n = BB * hh * ww;
            hipMemsetAsync(acc, 0, (size_t)BB * 3 * hh * ww * sizeof(float),
                           stream);
            splat_kernel<<<(n + 255) / 256, 256, 0, stream>>>(
                flows[d][s], zb[d], tgt, d, acc, s, hh, ww);
            if (s == 0) {
                backwarp_out_kernel<<<(n + 255) / 256, 256, 0, stream>>>(
                    acc, inp[d], out, 3, 512, 512, 70, d ? 35 : 0);
                backwarp_out_kernel<<<(n + 255) / 256, 256, 0, stream>>>(
                    acc, fea1[d], out, 32, 512, 512, 70, d ? 38 : 3);
            } else if (s == 1) {
                backwarp_out_kernel<<<(n + 255) / 256, 256, 0, stream>>>(
                    acc, fea2[d], out + l1off, 64, 256, 256, 128, d ? 64 : 0);
            } else {
                backwarp_out_kernel<<<(n + 255) / 256, 256, 0, stream>>>(
                    acc, fea3[d], out + l2off, 96, 128, 128, 192, d ? 96 : 0);
            }
        }
    }
}